// Round 13
// baseline (173.723 us; speedup 1.0000x reference)
//
#include <hip/hip_runtime.h>

// B=16, K=64 -> N=1024 images 28x28; conv1: 1->32ch 12x12; conv2: 32->64ch 4x4
// FLAT=1024, HID=D=128, OUT=S=128, m=64.
//
// out[b,s,i,j] = PP[i,j] + U[i] + V[j] + W + delta_ij*(D[i] + dconst)
// PP = sum_d a[s,d] f_i f_j ; U/V/D from g=f^2, r=f*S ; W,dconst from t=sum f^2, A=S^2
//
// NOTE: no float atomics anywhere — the harness's post-timing check requires
// bit-deterministic output across replays; final reduction is a fixed-order
// shfl tree in k_final.

#define FS_IDX(r, d) (((r) << 7) + (((((d) >> 2) ^ (((r) >> 2) & 7))) << 2) + ((d) & 3))

// ---------------------------------------------------------------------------
// K0: one-time prep. Coeff combine -> [s][d] matrices; fc_w transpose ->
// fcwT[k][s]; w2 reshape -> w2R[oc][ky][kx][ic].
// ---------------------------------------------------------------------------
__global__ __launch_bounds__(256) void k_prep(
        const float* __restrict__ coeffs, const float* __restrict__ fc_w,
        const float* __restrict__ w2,
        float* __restrict__ CaT,  float* __restrict__ CdgT, float* __restrict__ CdrT,
        float* __restrict__ CugT, float* __restrict__ CurT,
        float* __restrict__ CvgT, float* __restrict__ CvrT,
        float* __restrict__ CctT, float* __restrict__ CcAT,
        float* __restrict__ CwtT, float* __restrict__ CwAT,
        float* __restrict__ fcwT, float* __restrict__ w2R) {
    int idx = blockIdx.x * 256 + threadIdx.x;
    if (idx < 16384) {
        int d = idx >> 7, s = idx & 127;
        const float* c = coeffs + idx * 15;        // coeffs[d][s][p]
        const float im = 1.0f / 64.0f, im2 = 1.0f / 4096.0f;
        int t = s * 128 + d;                       // [s][d] layout
        CaT[t]  = c[9] + c[10];
        CdgT[t] = c[0];
        CdrT[t] = (c[2] + c[3]) * im;
        CurT[t] = (c[5] + c[6]) * im;
        CugT[t] = c[11];
        CvrT[t] = (c[7] + c[8]) * im;
        CvgT[t] = c[12];
        CctT[t] = c[1] * im;
        CcAT[t] = c[4] * im2;
        CwtT[t] = c[13] * im;
        CwAT[t] = c[14] * im2;
    } else if (idx < 147456) {
        int e = idx - 16384;                       // e = s*1024 + k
        int s = e >> 10, k = e & 1023;
        fcwT[k * 128 + s] = fc_w[e];
    } else if (idx < 198656) {
        int e = idx - 147456;                      // e = ((oc*5+ky)*5+kx)*32+ic
        int ic = e & 31;
        int q = e >> 5;
        int kx = q % 5, q2 = q / 5, ky = q2 % 5, oc = q2 / 5;
        w2R[e] = w2[oc * 800 + ic * 25 + ky * 5 + kx];
    }
}

// ---------------------------------------------------------------------------
// K1: fused conv1 + conv2 + fc, ONE image per block (1024 blocks, ~35.3KB LDS
// -> 4 blocks/CU). conv1: 768 half-row tasks (6 outputs each) = exactly 3 per
// thread; writes transposed c1T[pos][ic] (row stride 36). conv2: thread =
// (oc, icg): 16 outputs over an 8-ic slice, ~72 live VGPRs, 2-shfl reduce.
// fc: thread=(kc,sg): float4 weights, 8 FMA per 16B load.
// ---------------------------------------------------------------------------
__global__ __launch_bounds__(256) void k_convfc(
        const float* __restrict__ x,  const float* __restrict__ w1,
        const float* __restrict__ b1, const float* __restrict__ w2R,
        const float* __restrict__ b2, const float* __restrict__ fcwT,
        const float* __restrict__ fc_b, float* __restrict__ feat) {
    __shared__ alignas(16) float xs[784];
    __shared__ alignas(16) float w1s[800];
    __shared__ alignas(16) float c1T[144 * 36];    // [pos 144][ic 32 +4 pad]
    __shared__ alignas(16) float ysh[1024];
    __shared__ alignas(16) float ps[8][128];
    int tid = threadIdx.x;
    int n = blockIdx.x;

    {   // stage image + conv1 weights
        const float4* xsrc = (const float4*)(x + n * 784);
        float4* xdst = (float4*)xs;
        for (int i = tid; i < 196; i += 256) xdst[i] = xsrc[i];
        const float4* wsrc = (const float4*)w1;
        float4* wdst = (float4*)w1s;
        for (int i = tid; i < 200; i += 256) wdst[i] = wsrc[i];
    }
    __syncthreads();

    // ---- conv1: 768 half-row tasks, 3 per thread. task=(oy, oh, oc) ----
#pragma unroll
    for (int rep = 0; rep < 3; ++rep) {
        int task = rep * 256 + tid;
        int oc = task & 31, oh = (task >> 5) & 1, oy = task >> 6;
        const float* wp = w1s + oc * 25;
        float wr[25];
#pragma unroll
        for (int t = 0; t < 25; ++t) wr[t] = wp[t];
        float out[6];
        float bv = b1[oc];
#pragma unroll
        for (int ox = 0; ox < 6; ++ox) out[ox] = bv;
        const float* xb = xs + (oy * 2) * 28 + oh * 12;
#pragma unroll
        for (int ky = 0; ky < 5; ++ky) {
            const float4* rp = (const float4*)(xb + ky * 28 - oh * 12) + 3 * oh;
            float4 r0 = rp[0], r1 = rp[1], r2 = rp[2], r3 = rp[3];
            float rf[16] = {r0.x, r0.y, r0.z, r0.w, r1.x, r1.y, r1.z, r1.w,
                            r2.x, r2.y, r2.z, r2.w, r3.x, r3.y, r3.z, r3.w};
#pragma unroll
            for (int kx = 0; kx < 5; ++kx) {
                float wv = wr[ky * 5 + kx];
#pragma unroll
                for (int ox = 0; ox < 6; ++ox)
                    out[ox] = fmaf(rf[2 * ox + kx], wv, out[ox]);
            }
        }
#pragma unroll
        for (int ox = 0; ox < 6; ++ox)
            c1T[(oy * 12 + oh * 6 + ox) * 36 + oc] = fmaxf(out[ox], 0.0f);
    }
    __syncthreads();

    // ---- conv2: tid = oc*4 + icg; 8-ic slice, 16 outputs ----
    {
        int icg = tid & 3, oc = tid >> 2;
        int ic0 = icg * 8;
        float acc[16];
#pragma unroll
        for (int p = 0; p < 16; ++p) acc[p] = 0.0f;
        for (int ky = 0; ky < 5; ++ky) {
            float4 wv[5][2];
#pragma unroll
            for (int kx = 0; kx < 5; ++kx) {
                const float* wb = &w2R[((oc * 5 + ky) * 5 + kx) * 32 + ic0];
                wv[kx][0] = *(const float4*)(wb);
                wv[kx][1] = *(const float4*)(wb + 4);
            }
#pragma unroll
            for (int oyy = 0; oyy < 4; ++oyy) {
                int y = 2 * oyy + ky;
                const float* rowb = c1T + (y * 12) * 36 + ic0;
#pragma unroll
                for (int xx = 0; xx < 12; ++xx) {
                    float4 v0 = *(const float4*)(rowb + xx * 36);
                    float4 v1 = *(const float4*)(rowb + xx * 36 + 4);
#pragma unroll
                    for (int ox = 0; ox < 4; ++ox) {
                        int kx = xx - 2 * ox;
                        if (kx >= 0 && kx < 5) {
                            float4 w0 = wv[kx][0], w1v = wv[kx][1];
                            float s = acc[oyy * 4 + ox];
                            s = fmaf(v0.x, w0.x, s);
                            s = fmaf(v0.y, w0.y, s);
                            s = fmaf(v0.z, w0.z, s);
                            s = fmaf(v0.w, w0.w, s);
                            s = fmaf(v1.x, w1v.x, s);
                            s = fmaf(v1.y, w1v.y, s);
                            s = fmaf(v1.z, w1v.z, s);
                            s = fmaf(v1.w, w1v.w, s);
                            acc[oyy * 4 + ox] = s;
                        }
                    }
                }
            }
        }
#pragma unroll
        for (int m = 1; m < 4; m <<= 1)
#pragma unroll
            for (int p = 0; p < 16; ++p)
                acc[p] += __shfl_xor(acc[p], m);
        if (icg == 0) {
            float bb = b2[oc];
#pragma unroll
            for (int p = 0; p < 16; ++p)
                ysh[oc * 16 + p] = fmaxf(acc[p] + bb, 0.0f);
        }
    }
    __syncthreads();

    // ---- fc: tid = kc*32 + sg ----
    {
        int sg = tid & 31, kc = tid >> 5;
        const float* yb = &ysh[kc * 128];
        const float* wb = fcwT + kc * 128 * 128 + sg * 4;
        float4 a0 = {0.f, 0.f, 0.f, 0.f};
#pragma unroll 4
        for (int i = 0; i < 128; ++i) {
            float4 w = *(const float4*)(wb + i * 128);
            float y0 = yb[i];
            a0.x = fmaf(y0, w.x, a0.x); a0.y = fmaf(y0, w.y, a0.y);
            a0.z = fmaf(y0, w.z, a0.z); a0.w = fmaf(y0, w.w, a0.w);
        }
        *(float4*)&ps[kc][sg * 4] = a0;
    }
    __syncthreads();
    if (tid < 128) {
        int s = tid;
        float acc = fc_b[s];
#pragma unroll
        for (int kc = 0; kc < 8; ++kc) acc += ps[kc][s];
        feat[n * 128 + s] = acc;
    }
}

// ---------------------------------------------------------------------------
// K2: one block per (b, s-pair): 1024 blocks, 2 s each (~36KB LDS -> 4
// blocks/CU). Stages feat[b] (FS_IDX swizzle), stats + dconst/W + D/U/V for
// 2 s, 64x64x128 Gram with a[s,d] folded in-register, fused epilogue ->
// deterministic partial write (NO atomics).
// ---------------------------------------------------------------------------
__global__ __launch_bounds__(256) void k_main2(
        const float* __restrict__ feat,
        const float* __restrict__ CaT,  const float* __restrict__ CdgT,
        const float* __restrict__ CdrT, const float* __restrict__ CugT,
        const float* __restrict__ CurT, const float* __restrict__ CvgT,
        const float* __restrict__ CvrT, const float* __restrict__ CctT,
        const float* __restrict__ CcAT, const float* __restrict__ CwtT,
        const float* __restrict__ CwAT,
        const float* __restrict__ eq_bias, const float* __restrict__ diag_bias,
        const float* __restrict__ out_w,
        float* __restrict__ partials) {
    __shared__ alignas(16) float fs[8192];
    __shared__ alignas(16) float ash2[256];        // [d][sl]
    __shared__ alignas(16) float Ssh[128];
    __shared__ float Uv[2][64], Vv[2][64], Dv[2][64];
    __shared__ float parts[2][4];                  // [wave01][dc0,dc1,w0,w1]
    __shared__ float red[4][2];                    // [wave][sl]
    int b = blockIdx.x >> 6, sq = blockIdx.x & 63;
    int s0 = sq * 2;
    int tid = threadIdx.x;
    const float* fb = feat + b * 8192;

    // phase 0: stage
    for (int i = tid; i < 8192; i += 256) {
        int r = i >> 7, d = i & 127;
        fs[FS_IDX(r, d)] = fb[i];
    }
    if (tid < 256) {
        int d = tid >> 1, sl = tid & 1;
        ash2[d * 2 + sl] = CaT[(s0 + sl) * 128 + d];
    }
    __syncthreads();

    // phase 2: S/T per d + dconst/W partials (threads 0..127)
    if (tid < 128) {
        int d = tid;
        float sv = 0.f, tv = 0.f;
        for (int r = 0; r < 64; ++r) {
            float v = fs[FS_IDX(r, d)];
            sv += v;
            tv = fmaf(v, v, tv);
        }
        Ssh[d] = sv;
        float av = sv * sv;
        float dc[2], wv[2];
#pragma unroll
        for (int sl = 0; sl < 2; ++sl) {
            int o = (s0 + sl) * 128 + d;
            dc[sl] = fmaf(CctT[o], tv, CcAT[o] * av);
            wv[sl] = fmaf(CwtT[o], tv, CwAT[o] * av);
        }
#pragma unroll
        for (int m = 1; m < 64; m <<= 1)
#pragma unroll
            for (int sl = 0; sl < 2; ++sl) {
                dc[sl] += __shfl_xor(dc[sl], m);
                wv[sl] += __shfl_xor(wv[sl], m);
            }
        if ((tid & 63) == 0) {
            int w = tid >> 6;
#pragma unroll
            for (int sl = 0; sl < 2; ++sl) {
                parts[w][sl] = dc[sl];
                parts[w][2 + sl] = wv[sl];
            }
        }
    }
    __syncthreads();

    // phase 3: D/U/V for 2 s. thread (ty=tid>>4: rows ty*4+u, tx=tid&15: d0=tx*8)
    int tx = tid & 15, ty = tid >> 4;
    {
        int d0 = tx * 8;
        float4 s0v = *(const float4*)&Ssh[d0];
        float4 s1v = *(const float4*)&Ssh[d0 + 4];
        float sv[8] = {s0v.x, s0v.y, s0v.z, s0v.w, s1v.x, s1v.y, s1v.z, s1v.w};
#pragma unroll
        for (int sl = 0; sl < 2; ++sl) {
            int o = (s0 + sl) * 128 + d0;
            float4 A0, A1;
#define LD8(arr, p) A0 = *(const float4*)&arr[o]; A1 = *(const float4*)&arr[o + 4]; \
            float p[8] = {A0.x, A0.y, A0.z, A0.w, A1.x, A1.y, A1.z, A1.w};
            LD8(CdgT, cg) LD8(CdrT, cr) LD8(CugT, ug) LD8(CurT, ur) LD8(CvgT, vg) LD8(CvrT, vr)
#undef LD8
            float pD[4], pU[4], pV[4];
#pragma unroll
            for (int u = 0; u < 4; ++u) {
                int i = ty * 4 + u;
                float4 fA = *(const float4*)&fs[FS_IDX(i, d0)];
                float4 fB = *(const float4*)&fs[FS_IDX(i, d0 + 4)];
                float fv[8] = {fA.x, fA.y, fA.z, fA.w, fB.x, fB.y, fB.z, fB.w};
                float aD = 0.f, aU = 0.f, aV = 0.f;
#pragma unroll
                for (int e = 0; e < 8; ++e) {
                    float g = fv[e] * fv[e];
                    float rr = fv[e] * sv[e];
                    aD = fmaf(cg[e], g, fmaf(cr[e], rr, aD));
                    aU = fmaf(ug[e], g, fmaf(ur[e], rr, aU));
                    aV = fmaf(vg[e], g, fmaf(vr[e], rr, aV));
                }
                pD[u] = aD; pU[u] = aU; pV[u] = aV;
            }
#pragma unroll
            for (int m = 1; m < 16; m <<= 1)
#pragma unroll
                for (int u = 0; u < 4; ++u) {
                    pD[u] += __shfl_xor(pD[u], m);
                    pU[u] += __shfl_xor(pU[u], m);
                    pV[u] += __shfl_xor(pV[u], m);
                }
            if (tx == 0)
#pragma unroll
                for (int u = 0; u < 4; ++u) {
                    Dv[sl][ty * 4 + u] = pD[u];
                    Uv[sl][ty * 4 + u] = pU[u];
                    Vv[sl][ty * 4 + u] = pV[u];
                }
        }
    }
    __syncthreads();

    // phase 4: Gram for 2 s. rows i=4ty.., cols j=4tx..
    float acc[2][16];
#pragma unroll
    for (int sl = 0; sl < 2; ++sl)
#pragma unroll
        for (int q = 0; q < 16; ++q) acc[sl][q] = 0.f;
    for (int d = 0; d < 128; d += 4) {
        float aif[4][4], bjf[4][4], a4f[4][2];
#pragma unroll
        for (int u = 0; u < 4; ++u) {
            float4 t = *(const float4*)&fs[FS_IDX(ty * 4 + u, d)];
            aif[u][0] = t.x; aif[u][1] = t.y; aif[u][2] = t.z; aif[u][3] = t.w;
        }
#pragma unroll
        for (int v = 0; v < 4; ++v) {
            float4 t = *(const float4*)&fs[FS_IDX(tx * 4 + v, d)];
            bjf[v][0] = t.x; bjf[v][1] = t.y; bjf[v][2] = t.z; bjf[v][3] = t.w;
        }
#pragma unroll
        for (int dd = 0; dd < 2; ++dd) {
            float4 t = *(const float4*)&ash2[(d + dd * 2) * 2];
            a4f[dd * 2][0] = t.x;     a4f[dd * 2][1] = t.y;
            a4f[dd * 2 + 1][0] = t.z; a4f[dd * 2 + 1][1] = t.w;
        }
#pragma unroll
        for (int dd = 0; dd < 4; ++dd)
#pragma unroll
            for (int sl = 0; sl < 2; ++sl)
#pragma unroll
                for (int u = 0; u < 4; ++u) {
                    float t = aif[u][dd] * a4f[dd][sl];
#pragma unroll
                    for (int v = 0; v < 4; ++v)
                        acc[sl][u * 4 + v] = fmaf(t, bjf[v][dd], acc[sl][u * 4 + v]);
                }
    }

    // phase 5: epilogue + reduce + deterministic partial write
    float sDc[2], sW[2];
#pragma unroll
    for (int sl = 0; sl < 2; ++sl) {
        sDc[sl] = parts[0][sl] + parts[1][sl] + diag_bias[s0 + sl];
        sW[sl]  = parts[0][2 + sl] + parts[1][2 + sl] + eq_bias[s0 + sl];
    }
    float psum[2] = {0.f, 0.f};
#pragma unroll
    for (int u = 0; u < 4; ++u) {
        int i = ty * 4 + u;
#pragma unroll
        for (int v = 0; v < 4; ++v) {
            int j = tx * 4 + v;
#pragma unroll
            for (int sl = 0; sl < 2; ++sl) {
                float val = acc[sl][u * 4 + v] + Uv[sl][i] + Vv[sl][j] + sW[sl];
                if (i == j) val += Dv[sl][i] + sDc[sl];
                psum[sl] += fmaxf(val, 0.0f);
            }
        }
    }
#pragma unroll
    for (int m = 1; m < 64; m <<= 1)
#pragma unroll
        for (int sl = 0; sl < 2; ++sl) psum[sl] += __shfl_xor(psum[sl], m);
    if ((tid & 63) == 0) {
        int w = tid >> 6;
#pragma unroll
        for (int sl = 0; sl < 2; ++sl) red[w][sl] = psum[sl];
    }
    __syncthreads();
    if (tid == 0) {
        float o = 0.f;
#pragma unroll
        for (int sl = 0; sl < 2; ++sl) {
            float tot = red[0][sl] + red[1][sl] + red[2][sl] + red[3][sl];
            o += fmaxf(tot * (1.0f / 4096.0f), 0.0f) * out_w[s0 + sl];
        }
        partials[blockIdx.x] = o;                  // [b*64 + sq], deterministic
    }
}

// ---------------------------------------------------------------------------
// K3: deterministic final reduction. 16 blocks x 64 threads; fixed-order
// butterfly tree over the 64 partials of each batch element.
// ---------------------------------------------------------------------------
__global__ __launch_bounds__(64) void k_final(
        const float* __restrict__ partials, const float* __restrict__ out_b,
        float* __restrict__ dout) {
    int b = blockIdx.x, lane = threadIdx.x;
    float v = partials[b * 64 + lane];
#pragma unroll
    for (int m = 1; m < 64; m <<= 1) v += __shfl_xor(v, m);
    if (lane == 0) dout[b] = v + out_b[0];
}

extern "C" void kernel_launch(void* const* d_in, const int* in_sizes, int n_in,
                              void* d_out, int out_size, void* d_ws, size_t ws_size,
                              hipStream_t stream) {
    const float* x      = (const float*)d_in[0];
    const float* w1     = (const float*)d_in[1];
    const float* b1     = (const float*)d_in[2];
    const float* w2     = (const float*)d_in[3];
    const float* b2     = (const float*)d_in[4];
    const float* fc_w   = (const float*)d_in[5];
    const float* fc_b   = (const float*)d_in[6];
    const float* coeffs = (const float*)d_in[7];
    const float* eqb    = (const float*)d_in[8];
    const float* dgb    = (const float*)d_in[9];
    const float* out_w  = (const float*)d_in[10];
    const float* out_b  = (const float*)d_in[11];

    float* ws = (float*)d_ws;
    float* feat = ws; ws += 131072;    // (1024,128)
    float* fcwT = ws; ws += 131072;    // (1024,128)
    float* w2R  = ws; ws += 51200;     // (64,5,5,32)
    float* prt  = ws; ws += 1024;      // per-block partials (16 b x 64 sq)
    float* CaT  = ws; ws += 16384;
    float* CdgT = ws; ws += 16384;
    float* CdrT = ws; ws += 16384;
    float* CugT = ws; ws += 16384;
    float* CurT = ws; ws += 16384;
    float* CvgT = ws; ws += 16384;
    float* CvrT = ws; ws += 16384;
    float* CctT = ws; ws += 16384;
    float* CcAT = ws; ws += 16384;
    float* CwtT = ws; ws += 16384;
    float* CwAT = ws; ws += 16384;

    k_prep<<<776, 256, 0, stream>>>(coeffs, fc_w, w2,
                                    CaT, CdgT, CdrT, CugT, CurT, CvgT, CvrT,
                                    CctT, CcAT, CwtT, CwAT, fcwT, w2R);
    k_convfc<<<1024, 256, 0, stream>>>(x, w1, b1, w2R, b2, fcwT, fc_b, feat);
    k_main2<<<1024, 256, 0, stream>>>(feat, CaT, CdgT, CdrT, CugT, CurT,
                                      CvgT, CvrT, CctT, CcAT, CwtT, CwAT,
                                      eqb, dgb, out_w, prt);
    k_final<<<16, 64, 0, stream>>>(prt, out_b, (float*)d_out);
}